// Round 1
// baseline (2471.521 us; speedup 1.0000x reference)
//
#include <hip/hip_runtime.h>
#include <math.h>

#define NB  1024
#define NN  256
#define NF  4
#define NK  3
#define BIG 32
#define HID 2
#define BN_EPS 1e-5f
#define FLT_BIG 3.402823466e38f

// ---------------------------------------------------------------------------
// Kernel 0: zero the BN-stat accumulator (8 doubles in d_ws)
// ---------------------------------------------------------------------------
__global__ void k_zero_ws(double* ws) {
    if (threadIdx.x < 8) ws[threadIdx.x] = 0.0;
}

// ---------------------------------------------------------------------------
// Kernel 1: BatchNorm statistics. Per-feature sum and sum-of-squares over all
// B*N rows, accumulated in fp64 (block partials -> 8 double atomics).
// ---------------------------------------------------------------------------
__global__ __launch_bounds__(256) void k_bn_reduce(const float4* __restrict__ x,
                                                   double* __restrict__ ws) {
    int tid = blockIdx.x * 256 + threadIdx.x;
    double s[8] = {0, 0, 0, 0, 0, 0, 0, 0};
    for (int r = tid; r < NB * NN; r += 256 * 256) {
        float4 v = x[r];
        s[0] += v.x; s[1] += v.y; s[2] += v.z; s[3] += v.w;
        s[4] += (double)v.x * v.x; s[5] += (double)v.y * v.y;
        s[6] += (double)v.z * v.z; s[7] += (double)v.w * v.w;
    }
#pragma unroll
    for (int off = 32; off > 0; off >>= 1) {
#pragma unroll
        for (int i = 0; i < 8; i++) s[i] += __shfl_down(s[i], off);
    }
    __shared__ double red[4][8];
    int w = threadIdx.x >> 6, lane = threadIdx.x & 63;
    if (lane == 0) {
#pragma unroll
        for (int i = 0; i < 8; i++) red[w][i] = s[i];
    }
    __syncthreads();
    if (threadIdx.x == 0) {
#pragma unroll
        for (int i = 0; i < 8; i++) {
            double t = red[0][i] + red[1][i] + red[2][i] + red[3][i];
            atomicAdd(&ws[i], t);
        }
    }
}

// ---------------------------------------------------------------------------
// Kernel 2: fused BN-normalize + encoder DynamicEdgeConv + decoder
// DynamicEdgeConv. One block per graph (256 threads = 1 thread per node).
// kNN top-3 (smallest distance, ties -> lowest index, self included) done by
// streaming insertion with strict '<' while scanning ascending m, which
// reproduces jax.lax.top_k's stable tie-break exactly.
// ---------------------------------------------------------------------------
__global__ __launch_bounds__(256) void k_edgenet(
    const float*  __restrict__ x,
    const float*  __restrict__ gmm, const float* __restrict__ bta,
    const float*  __restrict__ ew1, const float* __restrict__ eb1,
    const float*  __restrict__ ew2, const float* __restrict__ eb2,
    const float*  __restrict__ ew3, const float* __restrict__ eb3,
    const float*  __restrict__ dw1, const float* __restrict__ db1,
    const float*  __restrict__ dw2, const float* __restrict__ db2,
    const float*  __restrict__ dw3, const float* __restrict__ db3,
    const double* __restrict__ bnstat,
    float*        __restrict__ out)
{
    __shared__ float s_h[NN][NF];     // normalized input points
    __shared__ float s_sq[NN];        // |h|^2 (encoder)
    __shared__ float s_he[NN][HID];   // encoder output points
    __shared__ float s_sq2[NN];       // |he|^2 (decoder)
    __shared__ float sw[2758];        // all MLP weights, concatenated

    float* s_ew1 = sw;                // [8 x 32]  256
    float* s_eb1 = s_ew1 + 256;       //           32
    float* s_ew2 = s_eb1 + 32;        // [32 x 32] 1024
    float* s_eb2 = s_ew2 + 1024;      //           32
    float* s_ew3 = s_eb2 + 32;        // [32 x 2]  64
    float* s_eb3 = s_ew3 + 64;        //           2
    float* s_dw1 = s_eb3 + 2;         // [4 x 32]  128
    float* s_db1 = s_dw1 + 128;       //           32
    float* s_dw2 = s_db1 + 32;        // [32 x 32] 1024
    float* s_db2 = s_dw2 + 1024;      //           32
    float* s_dw3 = s_db2 + 32;        // [32 x 4]  128
    float* s_db3 = s_dw3 + 128;       //           4

    const int n = threadIdx.x;
    const int b = blockIdx.x;

    // cooperative weight staging
    s_ew1[n] = ew1[n];
    if (n < 32)  s_eb1[n] = eb1[n];
    for (int i = n; i < 1024; i += 256) s_ew2[i] = ew2[i];
    if (n < 32)  s_eb2[n] = eb2[n];
    if (n < 64)  s_ew3[n] = ew3[n];
    if (n < 2)   s_eb3[n] = eb3[n];
    if (n < 128) s_dw1[n] = dw1[n];
    if (n < 32)  s_db1[n] = db1[n];
    for (int i = n; i < 1024; i += 256) s_dw2[i] = dw2[i];
    if (n < 32)  s_db2[n] = db2[n];
    if (n < 128) s_dw3[n] = dw3[n];
    if (n < 4)   s_db3[n] = db3[n];

    // BatchNorm parameters (uniform across threads)
    const double cnt = (double)(NB * NN);
    float mu[NF], rstd[NF], gam[NF], bet[NF];
#pragma unroll
    for (int f = 0; f < NF; f++) {
        double m   = bnstat[f] / cnt;
        double var = bnstat[4 + f] / cnt - m * m;
        mu[f]   = (float)m;
        rstd[f] = 1.0f / sqrtf((float)var + BN_EPS);
        gam[f]  = gmm[f];
        bet[f]  = bta[f];
    }

    // normalize my node
    float4 xv = ((const float4*)x)[b * NN + n];
    float h0 = (xv.x - mu[0]) * rstd[0] * gam[0] + bet[0];
    float h1 = (xv.y - mu[1]) * rstd[1] * gam[1] + bet[1];
    float h2 = (xv.z - mu[2]) * rstd[2] * gam[2] + bet[2];
    float h3 = (xv.w - mu[3]) * rstd[3] * gam[3] + bet[3];
    s_h[n][0] = h0; s_h[n][1] = h1; s_h[n][2] = h2; s_h[n][3] = h3;
    float sq = h0 * h0 + h1 * h1 + h2 * h2 + h3 * h3;
    s_sq[n] = sq;
    __syncthreads();

    // ---------------- encoder kNN (k=3, includes self) ----------------
    float d0 = FLT_BIG, d1 = FLT_BIG, d2 = FLT_BIG;
    int   i0 = 0, i1 = 0, i2 = 0;
    for (int m = 0; m < NN; ++m) {
        float a0 = s_h[m][0], a1 = s_h[m][1], a2 = s_h[m][2], a3 = s_h[m][3];
        float dot = h0 * a0 + h1 * a1 + h2 * a2 + h3 * a3;
        float d = (sq + s_sq[m]) - 2.0f * dot;
        if (d < d2) {
            if (d < d1) {
                d2 = d1; i2 = i1;
                if (d < d0) { d1 = d0; i1 = i0; d0 = d; i0 = m; }
                else        { d1 = d;  i1 = m; }
            } else { d2 = d; i2 = m; }
        }
    }

    // ---------------- encoder messages + mean ----------------
    float ms0 = 0.0f, ms1 = 0.0f;
    int nidx[NK] = {i0, i1, i2};
    for (int k = 0; k < NK; ++k) {
        int j = nidx[k];
        float e[8];
        e[0] = h0; e[1] = h1; e[2] = h2; e[3] = h3;
        e[4] = s_h[j][0] - h0; e[5] = s_h[j][1] - h1;
        e[6] = s_h[j][2] - h2; e[7] = s_h[j][3] - h3;
        float t1[BIG];
#pragma unroll
        for (int o = 0; o < BIG; o++) {
            float acc = s_eb1[o];
#pragma unroll
            for (int i = 0; i < 8; i++) acc += e[i] * s_ew1[i * BIG + o];
            t1[o] = fmaxf(acc, 0.0f);
        }
        float t2[BIG];
#pragma unroll
        for (int o = 0; o < BIG; o++) {
            float acc = s_eb2[o];
#pragma unroll
            for (int i = 0; i < BIG; i++) acc += t1[i] * s_ew2[i * BIG + o];
            t2[o] = fmaxf(acc, 0.0f);
        }
#pragma unroll
        for (int o = 0; o < HID; o++) {
            float acc = s_eb3[o];
#pragma unroll
            for (int i = 0; i < BIG; i++) acc += t2[i] * s_ew3[i * HID + o];
            acc = fmaxf(acc, 0.0f);          // final_relu=True
            if (o == 0) ms0 += acc; else ms1 += acc;
        }
    }
    float he0 = ms0 / 3.0f, he1 = ms1 / 3.0f;
    s_he[n][0] = he0; s_he[n][1] = he1;
    float sqe = he0 * he0 + he1 * he1;
    s_sq2[n] = sqe;
    __syncthreads();

    // ---------------- decoder kNN ----------------
    d0 = FLT_BIG; d1 = FLT_BIG; d2 = FLT_BIG;
    i0 = 0; i1 = 0; i2 = 0;
    for (int m = 0; m < NN; ++m) {
        float a0 = s_he[m][0], a1 = s_he[m][1];
        float dot = he0 * a0 + he1 * a1;
        float d = (sqe + s_sq2[m]) - 2.0f * dot;
        if (d < d2) {
            if (d < d1) {
                d2 = d1; i2 = i1;
                if (d < d0) { d1 = d0; i1 = i0; d0 = d; i0 = m; }
                else        { d1 = d;  i1 = m; }
            } else { d2 = d; i2 = m; }
        }
    }

    // ---------------- decoder messages + mean ----------------
    float os[NF] = {0.0f, 0.0f, 0.0f, 0.0f};
    int didx[NK] = {i0, i1, i2};
    for (int k = 0; k < NK; ++k) {
        int j = didx[k];
        float e[4];
        e[0] = he0; e[1] = he1;
        e[2] = s_he[j][0] - he0; e[3] = s_he[j][1] - he1;
        float t1[BIG];
#pragma unroll
        for (int o = 0; o < BIG; o++) {
            float acc = s_db1[o];
#pragma unroll
            for (int i = 0; i < 4; i++) acc += e[i] * s_dw1[i * BIG + o];
            t1[o] = fmaxf(acc, 0.0f);
        }
        float t2[BIG];
#pragma unroll
        for (int o = 0; o < BIG; o++) {
            float acc = s_db2[o];
#pragma unroll
            for (int i = 0; i < BIG; i++) acc += t1[i] * s_dw2[i * BIG + o];
            t2[o] = fmaxf(acc, 0.0f);
        }
#pragma unroll
        for (int o = 0; o < NF; o++) {
            float acc = s_db3[o];
#pragma unroll
            for (int i = 0; i < BIG; i++) acc += t2[i] * s_dw3[i * NF + o];
            os[o] += acc;                    // final_relu=False
        }
    }
    float4 ov;
    ov.x = os[0] / 3.0f; ov.y = os[1] / 3.0f;
    ov.z = os[2] / 3.0f; ov.w = os[3] / 3.0f;
    ((float4*)out)[b * NN + n] = ov;
}

// ---------------------------------------------------------------------------
extern "C" void kernel_launch(void* const* d_in, const int* in_sizes, int n_in,
                              void* d_out, int out_size, void* d_ws, size_t ws_size,
                              hipStream_t stream) {
    const float* x   = (const float*)d_in[0];
    const float* gmm = (const float*)d_in[1];
    const float* bta = (const float*)d_in[2];
    const float* ew1 = (const float*)d_in[3];
    const float* eb1 = (const float*)d_in[4];
    const float* ew2 = (const float*)d_in[5];
    const float* eb2 = (const float*)d_in[6];
    const float* ew3 = (const float*)d_in[7];
    const float* eb3 = (const float*)d_in[8];
    const float* dw1 = (const float*)d_in[9];
    const float* db1 = (const float*)d_in[10];
    const float* dw2 = (const float*)d_in[11];
    const float* db2 = (const float*)d_in[12];
    const float* dw3 = (const float*)d_in[13];
    const float* db3 = (const float*)d_in[14];
    double* ws = (double*)d_ws;
    float* out = (float*)d_out;

    hipLaunchKernelGGL(k_zero_ws, dim3(1), dim3(64), 0, stream, ws);
    hipLaunchKernelGGL(k_bn_reduce, dim3(256), dim3(256), 0, stream,
                       (const float4*)x, ws);
    hipLaunchKernelGGL(k_edgenet, dim3(NB), dim3(256), 0, stream,
                       x, gmm, bta, ew1, eb1, ew2, eb2, ew3, eb3,
                       dw1, db1, dw2, db2, dw3, db3, ws, out);
}

// Round 2
// 299.455 us; speedup vs baseline: 8.2534x; 8.2534x over previous
//
#include <hip/hip_runtime.h>
#include <math.h>

#define NB  1024
#define NN  256
#define NF  4
#define NK  3
#define BIG 32
#define HID 2
#define BN_EPS 1e-5f
#define FLT_BIG 3.402823466e38f

typedef float f32x16 __attribute__((ext_vector_type(16)));

static __device__ __forceinline__ f32x16 splat16(float s) {
    f32x16 v;
#pragma unroll
    for (int k = 0; k < 16; ++k) v[k] = s;
    return v;
}

static __device__ __forceinline__ f32x16 relu16(f32x16 v) {
    return __builtin_elementwise_max(v, splat16(0.0f));
}

static __device__ __forceinline__ f32x16 ldw16(const float* __restrict__ p) {
    // uniform address -> compiler emits s_load_dwordx16 (weights in SGPRs)
    return *(const f32x16*)p;
}

// ---------------------------------------------------------------------------
// Kernel 0: zero the BN-stat accumulator (8 doubles in d_ws)
// ---------------------------------------------------------------------------
__global__ void k_zero_ws(double* ws) {
    if (threadIdx.x < 8) ws[threadIdx.x] = 0.0;
}

// ---------------------------------------------------------------------------
// Kernel 1: BatchNorm statistics (fp64 partials -> 8 double atomics)
// ---------------------------------------------------------------------------
__global__ __launch_bounds__(256) void k_bn_reduce(const float4* __restrict__ x,
                                                   double* __restrict__ ws) {
    int tid = blockIdx.x * 256 + threadIdx.x;
    double s[8] = {0, 0, 0, 0, 0, 0, 0, 0};
    for (int r = tid; r < NB * NN; r += 256 * 256) {
        float4 v = x[r];
        s[0] += v.x; s[1] += v.y; s[2] += v.z; s[3] += v.w;
        s[4] += (double)v.x * v.x; s[5] += (double)v.y * v.y;
        s[6] += (double)v.z * v.z; s[7] += (double)v.w * v.w;
    }
#pragma unroll
    for (int off = 32; off > 0; off >>= 1) {
#pragma unroll
        for (int i = 0; i < 8; i++) s[i] += __shfl_down(s[i], off);
    }
    __shared__ double red[4][8];
    int w = threadIdx.x >> 6, lane = threadIdx.x & 63;
    if (lane == 0) {
#pragma unroll
        for (int i = 0; i < 8; i++) red[w][i] = s[i];
    }
    __syncthreads();
    if (threadIdx.x == 0) {
#pragma unroll
        for (int i = 0; i < 8; i++) {
            double t = red[0][i] + red[1][i] + red[2][i] + red[3][i];
            atomicAdd(&ws[i], t);
        }
    }
}

// ---------------------------------------------------------------------------
// Kernel 2: fused BN-normalize + encoder conv + decoder conv.
// One block per graph, one thread per node. Hidden state in f32x16 vector
// registers (outer-product MLP); weights streamed through SGPRs (uniform
// global loads). Branchless stable top-3 (strict <, ascending scan ==
// jax.lax.top_k tie-breaking).
// ---------------------------------------------------------------------------
__global__ __launch_bounds__(256, 4) void k_edgenet(
    const float*  __restrict__ x,
    const float*  __restrict__ gmm, const float* __restrict__ bta,
    const float*  __restrict__ ew1, const float* __restrict__ eb1,
    const float*  __restrict__ ew2, const float* __restrict__ eb2,
    const float*  __restrict__ ew3, const float* __restrict__ eb3,
    const float*  __restrict__ dw1, const float* __restrict__ db1,
    const float*  __restrict__ dw2, const float* __restrict__ db2,
    const float*  __restrict__ dw3, const float* __restrict__ db3,
    const double* __restrict__ bnstat,
    float*        __restrict__ out)
{
    __shared__ float s_h[NN][NF];     // normalized input points
    __shared__ float s_sq[NN];        // |h|^2
    __shared__ float s_he[NN][HID];   // encoder output points
    __shared__ float s_sq2[NN];       // |he|^2

    const int n = threadIdx.x;
    const int b = blockIdx.x;

    // BatchNorm parameters (uniform)
    const double cnt = (double)(NB * NN);
    float mu[NF], rstd[NF];
#pragma unroll
    for (int f = 0; f < NF; f++) {
        double m   = bnstat[f] / cnt;
        double var = bnstat[4 + f] / cnt - m * m;
        mu[f]   = (float)m;
        rstd[f] = 1.0f / sqrtf((float)var + BN_EPS);
    }

    float4 xv = ((const float4*)x)[b * NN + n];
    float h0 = (xv.x - mu[0]) * rstd[0] * gmm[0] + bta[0];
    float h1 = (xv.y - mu[1]) * rstd[1] * gmm[1] + bta[1];
    float h2 = (xv.z - mu[2]) * rstd[2] * gmm[2] + bta[2];
    float h3 = (xv.w - mu[3]) * rstd[3] * gmm[3] + bta[3];
    s_h[n][0] = h0; s_h[n][1] = h1; s_h[n][2] = h2; s_h[n][3] = h3;
    float sq = h0 * h0 + h1 * h1 + h2 * h2 + h3 * h3;
    s_sq[n] = sq;
    __syncthreads();

    // ---------------- encoder kNN (k=3, branchless stable insertion) -------
    float d0 = FLT_BIG, d1 = FLT_BIG, d2 = FLT_BIG;
    int   i0 = 0, i1 = 0, i2 = 0;
    for (int m = 0; m < NN; ++m) {
        float a0 = s_h[m][0], a1 = s_h[m][1], a2 = s_h[m][2], a3 = s_h[m][3];
        float dot = h0 * a0 + h1 * a1 + h2 * a2 + h3 * a3;
        float d = (sq + s_sq[m]) - 2.0f * dot;
        bool c0 = d < d0, c1 = d < d1, c2 = d < d2;
        d2 = c1 ? d1 : (c2 ? d : d2);  i2 = c1 ? i1 : (c2 ? m : i2);
        d1 = c0 ? d0 : (c1 ? d : d1);  i1 = c0 ? i0 : (c1 ? m : i1);
        d0 = c0 ? d  : d0;             i0 = c0 ? m  : i0;
    }

    // ---------------- encoder messages + mean ------------------------------
    float ms0 = 0.0f, ms1 = 0.0f;
#pragma unroll 1
    for (int k = 0; k < NK; ++k) {
        int j = (k == 0) ? i0 : ((k == 1) ? i1 : i2);
        float e0 = h0, e1 = h1, e2 = h2, e3 = h3;
        float e4 = s_h[j][0] - h0, e5 = s_h[j][1] - h1;
        float e6 = s_h[j][2] - h2, e7 = s_h[j][3] - h3;

        // layer 1: [8] -> [32]
        f32x16 h1a = ldw16(eb1), h1b = ldw16(eb1 + 16);
        {
            float es[8] = {e0, e1, e2, e3, e4, e5, e6, e7};
#pragma unroll
            for (int i = 0; i < 8; i++) {
                f32x16 s = splat16(es[i]);
                h1a += s * ldw16(ew1 + i * BIG);
                h1b += s * ldw16(ew1 + i * BIG + 16);
            }
        }
        h1a = relu16(h1a); h1b = relu16(h1b);

        // layer 2: [32] -> [32]
        f32x16 h2a = ldw16(eb2), h2b = ldw16(eb2 + 16);
#pragma unroll
        for (int i = 0; i < 16; i++) {
            f32x16 s = splat16(h1a[i]);
            h2a += s * ldw16(ew2 + i * BIG);
            h2b += s * ldw16(ew2 + i * BIG + 16);
        }
#pragma unroll
        for (int i = 0; i < 16; i++) {
            f32x16 s = splat16(h1b[i]);
            h2a += s * ldw16(ew2 + (16 + i) * BIG);
            h2b += s * ldw16(ew2 + (16 + i) * BIG + 16);
        }
        h2a = relu16(h2a); h2b = relu16(h2b);

        // layer 3: [32] -> [2], final relu
        float o0 = eb3[0], o1 = eb3[1];
#pragma unroll
        for (int i = 0; i < 16; i++) {
            o0 += h2a[i] * ew3[i * HID];
            o1 += h2a[i] * ew3[i * HID + 1];
        }
#pragma unroll
        for (int i = 0; i < 16; i++) {
            o0 += h2b[i] * ew3[(16 + i) * HID];
            o1 += h2b[i] * ew3[(16 + i) * HID + 1];
        }
        ms0 += fmaxf(o0, 0.0f);
        ms1 += fmaxf(o1, 0.0f);
    }
    float he0 = ms0 / 3.0f, he1 = ms1 / 3.0f;
    s_he[n][0] = he0; s_he[n][1] = he1;
    float sqe = he0 * he0 + he1 * he1;
    s_sq2[n] = sqe;
    __syncthreads();

    // ---------------- decoder kNN ------------------------------------------
    d0 = FLT_BIG; d1 = FLT_BIG; d2 = FLT_BIG;
    i0 = 0; i1 = 0; i2 = 0;
    for (int m = 0; m < NN; ++m) {
        float a0 = s_he[m][0], a1 = s_he[m][1];
        float dot = he0 * a0 + he1 * a1;
        float d = (sqe + s_sq2[m]) - 2.0f * dot;
        bool c0 = d < d0, c1 = d < d1, c2 = d < d2;
        d2 = c1 ? d1 : (c2 ? d : d2);  i2 = c1 ? i1 : (c2 ? m : i2);
        d1 = c0 ? d0 : (c1 ? d : d1);  i1 = c0 ? i0 : (c1 ? m : i1);
        d0 = c0 ? d  : d0;             i0 = c0 ? m  : i0;
    }

    // ---------------- decoder messages + mean ------------------------------
    float o0s = 0.0f, o1s = 0.0f, o2s = 0.0f, o3s = 0.0f;
#pragma unroll 1
    for (int k = 0; k < NK; ++k) {
        int j = (k == 0) ? i0 : ((k == 1) ? i1 : i2);
        float e0 = he0, e1 = he1;
        float e2 = s_he[j][0] - he0, e3 = s_he[j][1] - he1;

        // layer 1: [4] -> [32]
        f32x16 h1a = ldw16(db1), h1b = ldw16(db1 + 16);
        {
            float es[4] = {e0, e1, e2, e3};
#pragma unroll
            for (int i = 0; i < 4; i++) {
                f32x16 s = splat16(es[i]);
                h1a += s * ldw16(dw1 + i * BIG);
                h1b += s * ldw16(dw1 + i * BIG + 16);
            }
        }
        h1a = relu16(h1a); h1b = relu16(h1b);

        // layer 2: [32] -> [32]
        f32x16 h2a = ldw16(db2), h2b = ldw16(db2 + 16);
#pragma unroll
        for (int i = 0; i < 16; i++) {
            f32x16 s = splat16(h1a[i]);
            h2a += s * ldw16(dw2 + i * BIG);
            h2b += s * ldw16(dw2 + i * BIG + 16);
        }
#pragma unroll
        for (int i = 0; i < 16; i++) {
            f32x16 s = splat16(h1b[i]);
            h2a += s * ldw16(dw2 + (16 + i) * BIG);
            h2b += s * ldw16(dw2 + (16 + i) * BIG + 16);
        }
        h2a = relu16(h2a); h2b = relu16(h2b);

        // layer 3: [32] -> [4], no final relu
        float o0 = db3[0], o1 = db3[1], o2 = db3[2], o3 = db3[3];
#pragma unroll
        for (int i = 0; i < 16; i++) {
            float s = h2a[i];
            o0 += s * dw3[i * NF];
            o1 += s * dw3[i * NF + 1];
            o2 += s * dw3[i * NF + 2];
            o3 += s * dw3[i * NF + 3];
        }
#pragma unroll
        for (int i = 0; i < 16; i++) {
            float s = h2b[i];
            o0 += s * dw3[(16 + i) * NF];
            o1 += s * dw3[(16 + i) * NF + 1];
            o2 += s * dw3[(16 + i) * NF + 2];
            o3 += s * dw3[(16 + i) * NF + 3];
        }
        o0s += o0; o1s += o1; o2s += o2; o3s += o3;
    }
    float4 ov;
    ov.x = o0s / 3.0f; ov.y = o1s / 3.0f;
    ov.z = o2s / 3.0f; ov.w = o3s / 3.0f;
    ((float4*)out)[b * NN + n] = ov;
}

// ---------------------------------------------------------------------------
extern "C" void kernel_launch(void* const* d_in, const int* in_sizes, int n_in,
                              void* d_out, int out_size, void* d_ws, size_t ws_size,
                              hipStream_t stream) {
    const float* x   = (const float*)d_in[0];
    const float* gmm = (const float*)d_in[1];
    const float* bta = (const float*)d_in[2];
    const float* ew1 = (const float*)d_in[3];
    const float* eb1 = (const float*)d_in[4];
    const float* ew2 = (const float*)d_in[5];
    const float* eb2 = (const float*)d_in[6];
    const float* ew3 = (const float*)d_in[7];
    const float* eb3 = (const float*)d_in[8];
    const float* dw1 = (const float*)d_in[9];
    const float* db1 = (const float*)d_in[10];
    const float* dw2 = (const float*)d_in[11];
    const float* db2 = (const float*)d_in[12];
    const float* dw3 = (const float*)d_in[13];
    const float* db3 = (const float*)d_in[14];
    double* ws = (double*)d_ws;
    float* out = (float*)d_out;

    hipLaunchKernelGGL(k_zero_ws, dim3(1), dim3(64), 0, stream, ws);
    hipLaunchKernelGGL(k_bn_reduce, dim3(256), dim3(256), 0, stream,
                       (const float4*)x, ws);
    hipLaunchKernelGGL(k_edgenet, dim3(NB), dim3(256), 0, stream,
                       x, gmm, bta, ew1, eb1, ew2, eb2, ew3, eb3,
                       dw1, db1, dw2, db2, dw3, db3, ws, out);
}